// Round 3
// baseline (4357.748 us; speedup 1.0000x reference)
//
#include <hip/hip_runtime.h>
#include <math.h>

#define B_ROWS 32768
#define N_SLOTS 2048
#define H_DIM 512

#define BM 128
#define BN 128
#define BK 32
#define LDP 132   // padded LDS leading dim (132*4B % 16 == 0 keeps float4 alignment)
#define MCAP 4096

// zhat kernel tiling
#define ZRT 64    // rows per block
#define ZCT 128   // slot tile
#define ZBK 32
#define ZLA 68    // As pad: 68*4B % 16B == 0
#define ZLB 132
#define ZLP 132   // P pad

// ---------------- prep: reciprocal norms ----------------

__global__ __launch_bounds__(256) void prep_z_k(const float* __restrict__ z,
                                                float* __restrict__ zinv) {
    int row = blockIdx.x * 4 + (threadIdx.x >> 6);
    int lane = threadIdx.x & 63;
    const float4* p = reinterpret_cast<const float4*>(z + (size_t)row * H_DIM);
    float4 a = p[lane * 2];
    float4 b = p[lane * 2 + 1];
    float s = a.x * a.x + a.y * a.y + a.z * a.z + a.w * a.w
            + b.x * b.x + b.y * b.y + b.z * b.z + b.w * b.w;
#pragma unroll
    for (int m = 32; m >= 1; m >>= 1) s += __shfl_xor(s, m, 64);
    if (lane == 0) zinv[row] = 1.0f / fmaxf(sqrtf(s), 1e-12f);
}

__global__ __launch_bounds__(256) void prep_mem_k(const float* __restrict__ mem,
                                                  float* __restrict__ minv) {
    int row = blockIdx.x * 4 + (threadIdx.x >> 6);
    int lane = threadIdx.x & 63;
    const float4* p = reinterpret_cast<const float4*>(mem + (size_t)row * H_DIM);
    float4 a = p[lane * 2];
    float4 b = p[lane * 2 + 1];
    float s = a.x * a.x + a.y * a.y + a.z * a.z + a.w * a.w
            + b.x * b.x + b.y * b.y + b.z * b.z + b.w * b.w;
#pragma unroll
    for (int m = 32; m >= 1; m >>= 1) s += __shfl_xor(s, m, 64);
    if (lane == 0) minv[row] = 1.0f / fmaxf(sqrtf(s), 1e-12f);
}

// ---------------- stats: online softmax over all slot tiles, no sim store ----------------

__global__ __launch_bounds__(256) void stats_k(const float* __restrict__ A,
                                               const float* __restrict__ Bm,
                                               const float* __restrict__ zinv,
                                               const float* __restrict__ minv,
                                               float* __restrict__ rowmax,
                                               float* __restrict__ rowlinv,
                                               int* __restrict__ rowarg) {
    __shared__ float As[BK][LDP];
    __shared__ float Bs[BK][LDP];
    int tid = threadIdx.x;
    int row0 = blockIdx.x * BM;
    int tx = tid & 15, ty = tid >> 4;
    int lr = tid >> 3;          // 0..31
    int lk = (tid & 7) * 4;     // 0,4,...,28

    float zi[8];
#pragma unroll
    for (int i = 0; i < 8; ++i) zi[i] = zinv[row0 + ty * 8 + i];

    float runM[8], runL[8];
    int runA[8];
#pragma unroll
    for (int i = 0; i < 8; ++i) { runM[i] = -3.4e38f; runL[i] = 0.f; runA[i] = 0; }

    for (int ct = 0; ct < N_SLOTS / BN; ++ct) {
        int col0 = ct * BN;
        float acc[8][8];
#pragma unroll
        for (int i = 0; i < 8; ++i)
#pragma unroll
            for (int j = 0; j < 8; ++j) acc[i][j] = 0.f;

        for (int kc = 0; kc < H_DIM; kc += BK) {
#pragma unroll
            for (int it = 0; it < 4; ++it) {
                int r = it * 32 + lr;
                float4 va = *reinterpret_cast<const float4*>(A + (size_t)(row0 + r) * H_DIM + kc + lk);
                As[lk + 0][r] = va.x;
                As[lk + 1][r] = va.y;
                As[lk + 2][r] = va.z;
                As[lk + 3][r] = va.w;
                float4 vb = *reinterpret_cast<const float4*>(Bm + (size_t)(col0 + r) * H_DIM + kc + lk);
                Bs[lk + 0][r] = vb.x;
                Bs[lk + 1][r] = vb.y;
                Bs[lk + 2][r] = vb.z;
                Bs[lk + 3][r] = vb.w;
            }
            __syncthreads();
#pragma unroll 4
            for (int k = 0; k < BK; ++k) {
                const float4 a0 = *reinterpret_cast<const float4*>(&As[k][ty * 8]);
                const float4 a1 = *reinterpret_cast<const float4*>(&As[k][ty * 8 + 4]);
                const float4 b0 = *reinterpret_cast<const float4*>(&Bs[k][tx * 8]);
                const float4 b1 = *reinterpret_cast<const float4*>(&Bs[k][tx * 8 + 4]);
                float av[8] = {a0.x, a0.y, a0.z, a0.w, a1.x, a1.y, a1.z, a1.w};
                float bv[8] = {b0.x, b0.y, b0.z, b0.w, b1.x, b1.y, b1.z, b1.w};
#pragma unroll
                for (int i = 0; i < 8; ++i)
#pragma unroll
                    for (int j = 0; j < 8; ++j) acc[i][j] = fmaf(av[i], bv[j], acc[i][j]);
            }
            __syncthreads();
        }

        float mi[8];
#pragma unroll
        for (int j = 0; j < 8; ++j) mi[j] = minv[col0 + tx * 8 + j];

#pragma unroll
        for (int i = 0; i < 8; ++i) {
#pragma unroll
            for (int j = 0; j < 8; ++j) acc[i][j] *= zi[i] * mi[j];

            float lmax = acc[i][0];
            int larg = col0 + tx * 8;
#pragma unroll
            for (int j = 1; j < 8; ++j) {
                if (acc[i][j] > lmax) { lmax = acc[i][j]; larg = col0 + tx * 8 + j; }
            }
#pragma unroll
            for (int m = 8; m >= 1; m >>= 1) {
                float om = __shfl_xor(lmax, m, 16);
                int oa = __shfl_xor(larg, m, 16);
                if (om > lmax || (om == lmax && oa < larg)) { lmax = om; larg = oa; }
            }
            float ls = 0.f;
#pragma unroll
            for (int j = 0; j < 8; ++j) ls += expf(acc[i][j] - lmax);
#pragma unroll
            for (int m = 8; m >= 1; m >>= 1) ls += __shfl_xor(ls, m, 16);

            // online merge (all 16 lanes hold identical lmax/larg/ls -> redundant but raceless)
            if (lmax > runM[i]) {
                runL[i] = runL[i] * expf(runM[i] - lmax) + ls;
                runM[i] = lmax;
                runA[i] = larg;
            } else {
                runL[i] += ls * expf(lmax - runM[i]);
            }
        }
    }

    if (tx == 0) {
#pragma unroll
        for (int i = 0; i < 8; ++i) {
            int rg = row0 + ty * 8 + i;
            rowmax[rg] = runM[i];
            rowlinv[rg] = 1.0f / runL[i];
            rowarg[rg] = runA[i];
        }
    }
}

// ---------------- zhat: recompute S tiles with known stats, fuse P@V ----------------

__global__ __launch_bounds__(512) void zhat_k(const float* __restrict__ z,
                                              const float* __restrict__ mem,
                                              const float* __restrict__ zinv,
                                              const float* __restrict__ minv,
                                              const float* __restrict__ rowmax,
                                              const float* __restrict__ rowlinv,
                                              float* __restrict__ out) {
    __shared__ float As[ZBK][ZLA];
    __shared__ float Bs[ZBK][ZLB];
    __shared__ float P[ZRT][ZLP];
    __shared__ float Ms[ZRT], Ls[ZRT], Zi[ZRT];
    int tid = threadIdx.x;
    int row0 = blockIdx.x * ZRT;
    int tx = tid & 31, ty = tid >> 5;          // S phase: 4 slots x 4 rows per thread
    int ar = tid >> 3, ak = (tid & 7) * 4;     // A staging: 64 rows x 32 k
    int br = tid >> 2, bk = (tid & 3) * 8;     // B staging: 128 rows x 32 k
    int h0 = (tid & 31) * 16;                  // PV: 16 h-cols
    int rg4 = (tid >> 5) * 4;                  // PV: 4 rows

    if (tid < ZRT) {
        Ms[tid] = rowmax[row0 + tid];
        Ls[tid] = rowlinv[row0 + tid];
        Zi[tid] = zinv[row0 + tid];
    }
    float O[4][16];
#pragma unroll
    for (int i = 0; i < 4; ++i)
#pragma unroll
        for (int q = 0; q < 16; ++q) O[i][q] = 0.f;
    __syncthreads();

    for (int ct = 0; ct < N_SLOTS / ZCT; ++ct) {
        int col0 = ct * ZCT;
        float s[4][4];
#pragma unroll
        for (int i = 0; i < 4; ++i)
#pragma unroll
            for (int j = 0; j < 4; ++j) s[i][j] = 0.f;

        for (int kc = 0; kc < H_DIM; kc += ZBK) {
            {
                float4 va = *reinterpret_cast<const float4*>(z + (size_t)(row0 + ar) * H_DIM + kc + ak);
                As[ak + 0][ar] = va.x;
                As[ak + 1][ar] = va.y;
                As[ak + 2][ar] = va.z;
                As[ak + 3][ar] = va.w;
                float4 vb0 = *reinterpret_cast<const float4*>(mem + (size_t)(col0 + br) * H_DIM + kc + bk);
                float4 vb1 = *reinterpret_cast<const float4*>(mem + (size_t)(col0 + br) * H_DIM + kc + bk + 4);
                Bs[bk + 0][br] = vb0.x;
                Bs[bk + 1][br] = vb0.y;
                Bs[bk + 2][br] = vb0.z;
                Bs[bk + 3][br] = vb0.w;
                Bs[bk + 4][br] = vb1.x;
                Bs[bk + 5][br] = vb1.y;
                Bs[bk + 6][br] = vb1.z;
                Bs[bk + 7][br] = vb1.w;
            }
            __syncthreads();
#pragma unroll 4
            for (int k = 0; k < ZBK; ++k) {
                const float4 a = *reinterpret_cast<const float4*>(&As[k][ty * 4]);
                const float4 b = *reinterpret_cast<const float4*>(&Bs[k][tx * 4]);
                float av[4] = {a.x, a.y, a.z, a.w};
                float bv[4] = {b.x, b.y, b.z, b.w};
#pragma unroll
                for (int i = 0; i < 4; ++i)
#pragma unroll
                    for (int j = 0; j < 4; ++j) s[i][j] = fmaf(av[i], bv[j], s[i][j]);
            }
            __syncthreads();
        }

        // epilogue: P = exp(sim - M) * Linv into LDS
        float mi[4];
#pragma unroll
        for (int j = 0; j < 4; ++j) mi[j] = minv[col0 + tx * 4 + j];
#pragma unroll
        for (int i = 0; i < 4; ++i) {
            int r = ty * 4 + i;
            float zim = Zi[r], m = Ms[r], li = Ls[r];
            float4 pv;
            pv.x = expf(fminf(s[i][0] * zim * mi[0] - m, 30.f)) * li;
            pv.y = expf(fminf(s[i][1] * zim * mi[1] - m, 30.f)) * li;
            pv.z = expf(fminf(s[i][2] * zim * mi[2] - m, 30.f)) * li;
            pv.w = expf(fminf(s[i][3] * zim * mi[3] - m, 30.f)) * li;
            *reinterpret_cast<float4*>(&P[r][tx * 4]) = pv;
        }
        __syncthreads();

        // PV: O[4 rows][16 h] += P[r][c] * mem[col0+c][h]
        for (int c = 0; c < ZCT; ++c) {
            const float4* vp = reinterpret_cast<const float4*>(mem + (size_t)(col0 + c) * H_DIM + h0);
            float4 v0 = vp[0], v1 = vp[1], v2 = vp[2], v3 = vp[3];
            float vv[16] = {v0.x, v0.y, v0.z, v0.w, v1.x, v1.y, v1.z, v1.w,
                            v2.x, v2.y, v2.z, v2.w, v3.x, v3.y, v3.z, v3.w};
            float p0 = P[rg4 + 0][c], p1 = P[rg4 + 1][c], p2 = P[rg4 + 2][c], p3 = P[rg4 + 3][c];
#pragma unroll
            for (int q = 0; q < 16; ++q) {
                O[0][q] = fmaf(p0, vv[q], O[0][q]);
                O[1][q] = fmaf(p1, vv[q], O[1][q]);
                O[2][q] = fmaf(p2, vv[q], O[2][q]);
                O[3][q] = fmaf(p3, vv[q], O[3][q]);
            }
        }
        __syncthreads();
    }

#pragma unroll
    for (int i = 0; i < 4; ++i) {
        int r = row0 + rg4 + i;
        float4* dst = reinterpret_cast<float4*>(out + (size_t)r * H_DIM + h0);
        dst[0] = make_float4(O[i][0], O[i][1], O[i][2], O[i][3]);
        dst[1] = make_float4(O[i][4], O[i][5], O[i][6], O[i][7]);
        dst[2] = make_float4(O[i][8], O[i][9], O[i][10], O[i][11]);
        dst[3] = make_float4(O[i][12], O[i][13], O[i][14], O[i][15]);
    }
}

// ---------------- per-slot update: gather members, masked softmax, renormalize ----------------

__global__ __launch_bounds__(256) void slot_update_k(const float* __restrict__ mem,
                                                     const float* __restrict__ z,
                                                     const float* __restrict__ rowmax,
                                                     const int* __restrict__ rowarg,
                                                     float* __restrict__ outmem) {
    __shared__ int members[MCAP];
    __shared__ float uval[MCAP];
    __shared__ int cnt;
    __shared__ float red[4];
    __shared__ float bcast;
    int slot = blockIdx.x, tid = threadIdx.x;
    if (tid == 0) cnt = 0;
    __syncthreads();
    for (int b = tid; b < B_ROWS; b += 256) {
        if (rowarg[b] == slot) {
            int p = atomicAdd(&cnt, 1);
            if (p < MCAP) members[p] = b;
        }
    }
    __syncthreads();
    int n = min(cnt, MCAP);
    size_t base = (size_t)slot * H_DIM;
    if (n == 0) {
        for (int h = tid; h < H_DIM; h += 256) outmem[base + h] = mem[base + h];
        return;
    }
    // slot max over members' row maxima
    float lm = -3.4e38f;
    for (int j = tid; j < n; j += 256) lm = fmaxf(lm, rowmax[members[j]]);
#pragma unroll
    for (int m = 32; m >= 1; m >>= 1) lm = fmaxf(lm, __shfl_xor(lm, m, 64));
    if ((tid & 63) == 0) red[tid >> 6] = lm;
    __syncthreads();
    if (tid == 0) bcast = fmaxf(fmaxf(red[0], red[1]), fmaxf(red[2], red[3]));
    __syncthreads();
    float mslot = bcast;
    __syncthreads();
    // denom
    float ls = 0.f;
    for (int j = tid; j < n; j += 256) {
        float u = expf(rowmax[members[j]] - mslot);
        uval[j] = u;
        ls += u;
    }
#pragma unroll
    for (int m = 32; m >= 1; m >>= 1) ls += __shfl_xor(ls, m, 64);
    if ((tid & 63) == 0) red[tid >> 6] = ls;
    __syncthreads();
    if (tid == 0) bcast = (red[0] + red[1]) + (red[2] + red[3]);
    __syncthreads();
    float dinv = 1.0f / fmaxf(bcast, 1e-30f);
    // accumulate v = mem + sum_j u_j * z_j  (each thread owns 2 columns)
    float v0 = mem[base + tid];
    float v1 = mem[base + 256 + tid];
    for (int j = 0; j < n; ++j) {
        float u = uval[j] * dinv;
        size_t zb = (size_t)members[j] * H_DIM;
        v0 = fmaf(u, z[zb + tid], v0);
        v1 = fmaf(u, z[zb + 256 + tid], v1);
    }
    // normalize
    float s = v0 * v0 + v1 * v1;
#pragma unroll
    for (int m = 32; m >= 1; m >>= 1) s += __shfl_xor(s, m, 64);
    if ((tid & 63) == 0) red[tid >> 6] = s;
    __syncthreads();
    if (tid == 0) bcast = (red[0] + red[1]) + (red[2] + red[3]);
    __syncthreads();
    float ninv = 1.0f / fmaxf(sqrtf(bcast), 1e-12f);
    outmem[base + tid] = v0 * ninv;
    outmem[base + 256 + tid] = v1 * ninv;
}

// ---------------- launch ----------------

extern "C" void kernel_launch(void* const* d_in, const int* in_sizes, int n_in,
                              void* d_out, int out_size, void* d_ws, size_t ws_size,
                              hipStream_t stream) {
    const float* z = (const float*)d_in[0];
    const float* mem = (const float*)d_in[1];
    float* out_zhat = (float*)d_out;
    float* out_mem = out_zhat + (size_t)B_ROWS * H_DIM;

    char* ws = (char*)d_ws;
    size_t off = 0;
    auto alloc = [&](size_t bytes) -> void* {
        void* p = ws + off;
        off += (bytes + 255) & ~(size_t)255;
        return p;
    };
    float* rowmax = (float*)alloc((size_t)B_ROWS * 4);
    float* rowlinv = (float*)alloc((size_t)B_ROWS * 4);
    int* rowarg = (int*)alloc((size_t)B_ROWS * 4);
    float* zinv = (float*)alloc((size_t)B_ROWS * 4);
    float* minv = (float*)alloc((size_t)N_SLOTS * 4);
    // total ws use: ~528 KB

    prep_z_k<<<B_ROWS / 4, 256, 0, stream>>>(z, zinv);
    prep_mem_k<<<N_SLOTS / 4, 256, 0, stream>>>(mem, minv);
    stats_k<<<B_ROWS / BM, 256, 0, stream>>>(z, mem, zinv, minv, rowmax, rowlinv, rowarg);
    zhat_k<<<B_ROWS / ZRT, 512, 0, stream>>>(z, mem, zinv, minv, rowmax, rowlinv, out_zhat);
    slot_update_k<<<N_SLOTS, 256, 0, stream>>>(mem, z, rowmax, rowarg, out_mem);
}

// Round 4
// 1926.349 us; speedup vs baseline: 2.2622x; 2.2622x over previous
//
#include <hip/hip_runtime.h>
#include <math.h>

#define B_ROWS 32768
#define N_SLOTS 2048
#define H_DIM 512

#define BM 128
#define BN 128
#define BK 32
#define LDP 132   // padded LDS leading dim for fp32 stats kernel
#define MCAP 4096

typedef __attribute__((ext_vector_type(8))) short bf16x8;
typedef __attribute__((ext_vector_type(4))) float f32x4;

__device__ __forceinline__ unsigned short f2bf(float f) {
    unsigned u = __float_as_uint(f);
    unsigned r = 0x7fffu + ((u >> 16) & 1u);
    return (unsigned short)((u + r) >> 16);
}
__device__ __forceinline__ unsigned pk2(float a, float b) {
    return (unsigned)f2bf(a) | ((unsigned)f2bf(b) << 16);
}

// ---------------- prep: reciprocal norms ----------------

__global__ __launch_bounds__(256) void prep_z_k(const float* __restrict__ z,
                                                float* __restrict__ zinv) {
    int row = blockIdx.x * 4 + (threadIdx.x >> 6);
    int lane = threadIdx.x & 63;
    const float4* p = reinterpret_cast<const float4*>(z + (size_t)row * H_DIM);
    float4 a = p[lane * 2];
    float4 b = p[lane * 2 + 1];
    float s = a.x * a.x + a.y * a.y + a.z * a.z + a.w * a.w
            + b.x * b.x + b.y * b.y + b.z * b.z + b.w * b.w;
#pragma unroll
    for (int m = 32; m >= 1; m >>= 1) s += __shfl_xor(s, m, 64);
    if (lane == 0) zinv[row] = 1.0f / fmaxf(sqrtf(s), 1e-12f);
}

__global__ __launch_bounds__(256) void prep_mem_k(const float* __restrict__ mem,
                                                  float* __restrict__ minv) {
    int row = blockIdx.x * 4 + (threadIdx.x >> 6);
    int lane = threadIdx.x & 63;
    const float4* p = reinterpret_cast<const float4*>(mem + (size_t)row * H_DIM);
    float4 a = p[lane * 2];
    float4 b = p[lane * 2 + 1];
    float s = a.x * a.x + a.y * a.y + a.z * a.z + a.w * a.w
            + b.x * b.x + b.y * b.y + b.z * b.z + b.w * b.w;
#pragma unroll
    for (int m = 32; m >= 1; m >>= 1) s += __shfl_xor(s, m, 64);
    if (lane == 0) minv[row] = 1.0f / fmaxf(sqrtf(s), 1e-12f);
}

// ---------------- stats: fp32 online softmax (UNCHANGED — argmax fidelity) ----------------

__global__ __launch_bounds__(256) void stats_k(const float* __restrict__ A,
                                               const float* __restrict__ Bm,
                                               const float* __restrict__ zinv,
                                               const float* __restrict__ minv,
                                               float* __restrict__ rowmax,
                                               float* __restrict__ rowlinv,
                                               int* __restrict__ rowarg) {
    __shared__ float As[BK][LDP];
    __shared__ float Bs[BK][LDP];
    int tid = threadIdx.x;
    int row0 = blockIdx.x * BM;
    int tx = tid & 15, ty = tid >> 4;
    int lr = tid >> 3;          // 0..31
    int lk = (tid & 7) * 4;     // 0,4,...,28

    float zi[8];
#pragma unroll
    for (int i = 0; i < 8; ++i) zi[i] = zinv[row0 + ty * 8 + i];

    float runM[8], runL[8];
    int runA[8];
#pragma unroll
    for (int i = 0; i < 8; ++i) { runM[i] = -3.4e38f; runL[i] = 0.f; runA[i] = 0; }

    for (int ct = 0; ct < N_SLOTS / BN; ++ct) {
        int col0 = ct * BN;
        float acc[8][8];
#pragma unroll
        for (int i = 0; i < 8; ++i)
#pragma unroll
            for (int j = 0; j < 8; ++j) acc[i][j] = 0.f;

        for (int kc = 0; kc < H_DIM; kc += BK) {
#pragma unroll
            for (int it = 0; it < 4; ++it) {
                int r = it * 32 + lr;
                float4 va = *reinterpret_cast<const float4*>(A + (size_t)(row0 + r) * H_DIM + kc + lk);
                As[lk + 0][r] = va.x;
                As[lk + 1][r] = va.y;
                As[lk + 2][r] = va.z;
                As[lk + 3][r] = va.w;
                float4 vb = *reinterpret_cast<const float4*>(Bm + (size_t)(col0 + r) * H_DIM + kc + lk);
                Bs[lk + 0][r] = vb.x;
                Bs[lk + 1][r] = vb.y;
                Bs[lk + 2][r] = vb.z;
                Bs[lk + 3][r] = vb.w;
            }
            __syncthreads();
#pragma unroll 4
            for (int k = 0; k < BK; ++k) {
                const float4 a0 = *reinterpret_cast<const float4*>(&As[k][ty * 8]);
                const float4 a1 = *reinterpret_cast<const float4*>(&As[k][ty * 8 + 4]);
                const float4 b0 = *reinterpret_cast<const float4*>(&Bs[k][tx * 8]);
                const float4 b1 = *reinterpret_cast<const float4*>(&Bs[k][tx * 8 + 4]);
                float av[8] = {a0.x, a0.y, a0.z, a0.w, a1.x, a1.y, a1.z, a1.w};
                float bv[8] = {b0.x, b0.y, b0.z, b0.w, b1.x, b1.y, b1.z, b1.w};
#pragma unroll
                for (int i = 0; i < 8; ++i)
#pragma unroll
                    for (int j = 0; j < 8; ++j) acc[i][j] = fmaf(av[i], bv[j], acc[i][j]);
            }
            __syncthreads();
        }

        float mi[8];
#pragma unroll
        for (int j = 0; j < 8; ++j) mi[j] = minv[col0 + tx * 8 + j];

#pragma unroll
        for (int i = 0; i < 8; ++i) {
#pragma unroll
            for (int j = 0; j < 8; ++j) acc[i][j] *= zi[i] * mi[j];

            float lmax = acc[i][0];
            int larg = col0 + tx * 8;
#pragma unroll
            for (int j = 1; j < 8; ++j) {
                if (acc[i][j] > lmax) { lmax = acc[i][j]; larg = col0 + tx * 8 + j; }
            }
#pragma unroll
            for (int m = 8; m >= 1; m >>= 1) {
                float om = __shfl_xor(lmax, m, 16);
                int oa = __shfl_xor(larg, m, 16);
                if (om > lmax || (om == lmax && oa < larg)) { lmax = om; larg = oa; }
            }
            float ls = 0.f;
#pragma unroll
            for (int j = 0; j < 8; ++j) ls += expf(acc[i][j] - lmax);
#pragma unroll
            for (int m = 8; m >= 1; m >>= 1) ls += __shfl_xor(ls, m, 16);

            if (lmax > runM[i]) {
                runL[i] = runL[i] * expf(runM[i] - lmax) + ls;
                runM[i] = lmax;
                runA[i] = larg;
            } else {
                runL[i] += ls * expf(lmax - runM[i]);
            }
        }
    }

    if (tx == 0) {
#pragma unroll
        for (int i = 0; i < 8; ++i) {
            int rg = row0 + ty * 8 + i;
            rowmax[rg] = runM[i];
            rowlinv[rg] = 1.0f / runL[i];
            rowarg[rg] = runA[i];
        }
    }
}

// ---------------- zhat: bf16 MFMA — recompute S with known stats, fused P@V ----------------
// Block: 512 threads (8 waves), 64 rows. LDS ~54 KB.
// Layouts: Zc/Ml [row][k] stride 72 bf16; Pl/Vl stride 136 bf16 (both ≡4 dwords mod 32
// -> 2-way bank aliasing = free; 16B-aligned rows for ds_read_b128 fragments).

#define ZST 72
#define ZPL 136

__global__ __launch_bounds__(512, 2) void zhat_k(const float* __restrict__ z,
                                                 const float* __restrict__ mem,
                                                 const float* __restrict__ zinv,
                                                 const float* __restrict__ minv,
                                                 const float* __restrict__ rowmax,
                                                 const float* __restrict__ rowlinv,
                                                 float* __restrict__ out) {
    __shared__ __align__(16) short Pl[64 * ZPL];        // 17408 B
    __shared__ __align__(16) short Stage[192 * ZST];    // 27648 B: Zc[64*ZST] + Ml[128*ZST]; Vl aliases
    __shared__ float Mi[N_SLOTS];                       // 8192 B
    __shared__ float Ms[64], Ls[64], Zi[64];

    short* Zc = Stage;
    short* Ml = Stage + 64 * ZST;
    short* Vl = Stage;                                  // [64 h][128 slots] transposed V

    int tid = threadIdx.x;
    int row0 = blockIdx.x * 64;
    int wave = tid >> 6, lane = tid & 63;
    int lm = lane & 15, quad = lane >> 4;
    int rt = wave & 3;      // row-tile (16 rows) this wave owns
    int wg = wave >> 2;     // 0..1

    // staging index precompute
    int zr = tid >> 3, zk0 = (tid & 7) * 8;   // Zc: 64 rows x 8 k-octets
    int msl = tid >> 2, mk0 = (tid & 3) * 16; // Ml: 128 slots x 4 k-16s
    int vh = lane;                            // Vl: h row (0..63)

    for (int i = tid; i < N_SLOTS; i += 512) Mi[i] = minv[i];
    if (tid < 64) {
        Ms[tid] = rowmax[row0 + tid];
        Ls[tid] = rowlinv[row0 + tid];
        Zi[tid] = zinv[row0 + tid];
    }

    f32x4 acc[16];
#pragma unroll
    for (int t = 0; t < 16; ++t) acc[t] = (f32x4){0.f, 0.f, 0.f, 0.f};
    __syncthreads();

    for (int ct = 0; ct < 16; ++ct) {
        int col0 = ct * 128;

        // ---- S phase: S[64][128] = z-tile @ mem-tile^T over K=512 ----
        f32x4 sacc[4];
#pragma unroll
        for (int i = 0; i < 4; ++i) sacc[i] = (f32x4){0.f, 0.f, 0.f, 0.f};

        for (int kc = 0; kc < H_DIM; kc += 64) {
            {
                const float* src = z + (size_t)(row0 + zr) * H_DIM + kc + zk0;
                float4 a = *reinterpret_cast<const float4*>(src);
                float4 b = *reinterpret_cast<const float4*>(src + 4);
                uint4 pz = {pk2(a.x, a.y), pk2(a.z, a.w), pk2(b.x, b.y), pk2(b.z, b.w)};
                *reinterpret_cast<uint4*>(&Zc[zr * ZST + zk0]) = pz;

                const float* ms = mem + (size_t)(col0 + msl) * H_DIM + kc + mk0;
#pragma unroll
                for (int j = 0; j < 4; ++j) {
                    float4 v = *reinterpret_cast<const float4*>(ms + j * 4);
                    uint2 pm = {pk2(v.x, v.y), pk2(v.z, v.w)};
                    *reinterpret_cast<uint2*>(&Ml[msl * ZST + mk0 + j * 4]) = pm;
                }
            }
            __syncthreads();
#pragma unroll
            for (int ks = 0; ks < 2; ++ks) {
                bf16x8 af = *reinterpret_cast<const bf16x8*>(&Zc[(rt * 16 + lm) * ZST + ks * 32 + quad * 8]);
#pragma unroll
                for (int i = 0; i < 4; ++i) {
                    bf16x8 bfr = *reinterpret_cast<const bf16x8*>(&Ml[((wg * 4 + i) * 16 + lm) * ZST + ks * 32 + quad * 8]);
                    sacc[i] = __builtin_amdgcn_mfma_f32_16x16x32_bf16(af, bfr, sacc[i], 0, 0, 0);
                }
            }
            __syncthreads();
        }

        // ---- P transform: C-layout (col=lane&15, row=quad*4+reg) -> Pl[row][slot] ----
#pragma unroll
        for (int i = 0; i < 4; ++i) {
            int slot_l = (wg * 4 + i) * 16 + lm;
            float mv = Mi[col0 + slot_l];
#pragma unroll
            for (int r = 0; r < 4; ++r) {
                int rl = rt * 16 + quad * 4 + r;
                float s = sacc[i][r] * Zi[rl] * mv;
                float p = __expf(fminf(s - Ms[rl], 30.f)) * Ls[rl];
                Pl[rl * ZPL + slot_l] = (short)f2bf(p);
            }
        }
        __syncthreads();

        // ---- PV phase: O[64][512] += P[64][128] @ V[128][512], h-chunks of 64 ----
        for (int hc = 0; hc < 8; ++hc) {
            // stage Vl[h][slot] (transposed): coalesced global, 2-wayish LDS writes
#pragma unroll
            for (int it = 0; it < 4; ++it) {
                int s0 = wave * 4 + it * 32;
                const float* vs = mem + (size_t)(col0 + s0) * H_DIM + hc * 64 + vh;
                float f0 = vs[0], f1 = vs[H_DIM], f2 = vs[2 * H_DIM], f3 = vs[3 * H_DIM];
                uint2 pv = {pk2(f0, f1), pk2(f2, f3)};
                *reinterpret_cast<uint2*>(&Vl[vh * ZPL + s0]) = pv;
            }
            __syncthreads();
#pragma unroll
            for (int ks = 0; ks < 4; ++ks) {
                bf16x8 af = *reinterpret_cast<const bf16x8*>(&Pl[(rt * 16 + lm) * ZPL + ks * 32 + quad * 8]);
#pragma unroll
                for (int i = 0; i < 2; ++i) {
                    int hl = (wg * 2 + i) * 16 + lm;
                    bf16x8 bfr = *reinterpret_cast<const bf16x8*>(&Vl[hl * ZPL + ks * 32 + quad * 8]);
                    int t = hc * 2 + i;
                    acc[t] = __builtin_amdgcn_mfma_f32_16x16x32_bf16(af, bfr, acc[t], 0, 0, 0);
                }
            }
            __syncthreads();
        }
    }

    // ---- epilogue: C-layout -> global fp32 ----
#pragma unroll
    for (int hc = 0; hc < 8; ++hc)
#pragma unroll
        for (int i = 0; i < 2; ++i) {
            int t = hc * 2 + i;
            int h = hc * 64 + (wg * 2 + i) * 16 + lm;
#pragma unroll
            for (int r = 0; r < 4; ++r) {
                int rg = row0 + rt * 16 + quad * 4 + r;
                out[(size_t)rg * H_DIM + h] = acc[t][r];
            }
        }
}

// ---------------- per-slot update: gather members, masked softmax, renormalize ----------------

__global__ __launch_bounds__(256) void slot_update_k(const float* __restrict__ mem,
                                                     const float* __restrict__ z,
                                                     const float* __restrict__ rowmax,
                                                     const int* __restrict__ rowarg,
                                                     float* __restrict__ outmem) {
    __shared__ int members[MCAP];
    __shared__ float uval[MCAP];
    __shared__ int cnt;
    __shared__ float red[4];
    __shared__ float bcast;
    int slot = blockIdx.x, tid = threadIdx.x;
    if (tid == 0) cnt = 0;
    __syncthreads();
    for (int b = tid; b < B_ROWS; b += 256) {
        if (rowarg[b] == slot) {
            int p = atomicAdd(&cnt, 1);
            if (p < MCAP) members[p] = b;
        }
    }
    __syncthreads();
    int n = min(cnt, MCAP);
    size_t base = (size_t)slot * H_DIM;
    if (n == 0) {
        for (int h = tid; h < H_DIM; h += 256) outmem[base + h] = mem[base + h];
        return;
    }
    float lm = -3.4e38f;
    for (int j = tid; j < n; j += 256) lm = fmaxf(lm, rowmax[members[j]]);
#pragma unroll
    for (int m = 32; m >= 1; m >>= 1) lm = fmaxf(lm, __shfl_xor(lm, m, 64));
    if ((tid & 63) == 0) red[tid >> 6] = lm;
    __syncthreads();
    if (tid == 0) bcast = fmaxf(fmaxf(red[0], red[1]), fmaxf(red[2], red[3]));
    __syncthreads();
    float mslot = bcast;
    __syncthreads();
    float ls = 0.f;
    for (int j = tid; j < n; j += 256) {
        float u = expf(rowmax[members[j]] - mslot);
        uval[j] = u;
        ls += u;
    }
#pragma unroll
    for (int m = 32; m >= 1; m >>= 1) ls += __shfl_xor(ls, m, 64);
    if ((tid & 63) == 0) red[tid >> 6] = ls;
    __syncthreads();
    if (tid == 0) bcast = (red[0] + red[1]) + (red[2] + red[3]);
    __syncthreads();
    float dinv = 1.0f / fmaxf(bcast, 1e-30f);
    float v0 = mem[base + tid];
    float v1 = mem[base + 256 + tid];
    for (int j = 0; j < n; ++j) {
        float u = uval[j] * dinv;
        size_t zb = (size_t)members[j] * H_DIM;
        v0 = fmaf(u, z[zb + tid], v0);
        v1 = fmaf(u, z[zb + 256 + tid], v1);
    }
    float s = v0 * v0 + v1 * v1;
#pragma unroll
    for (int m = 32; m >= 1; m >>= 1) s += __shfl_xor(s, m, 64);
    if ((tid & 63) == 0) red[tid >> 6] = s;
    __syncthreads();
    if (tid == 0) bcast = (red[0] + red[1]) + (red[2] + red[3]);
    __syncthreads();
    float ninv = 1.0f / fmaxf(sqrtf(bcast), 1e-12f);
    outmem[base + tid] = v0 * ninv;
    outmem[base + 256 + tid] = v1 * ninv;
}

// ---------------- launch ----------------

extern "C" void kernel_launch(void* const* d_in, const int* in_sizes, int n_in,
                              void* d_out, int out_size, void* d_ws, size_t ws_size,
                              hipStream_t stream) {
    const float* z = (const float*)d_in[0];
    const float* mem = (const float*)d_in[1];
    float* out_zhat = (float*)d_out;
    float* out_mem = out_zhat + (size_t)B_ROWS * H_DIM;

    char* ws = (char*)d_ws;
    size_t off = 0;
    auto alloc = [&](size_t bytes) -> void* {
        void* p = ws + off;
        off += (bytes + 255) & ~(size_t)255;
        return p;
    };
    float* rowmax = (float*)alloc((size_t)B_ROWS * 4);
    float* rowlinv = (float*)alloc((size_t)B_ROWS * 4);
    int* rowarg = (int*)alloc((size_t)B_ROWS * 4);
    float* zinv = (float*)alloc((size_t)B_ROWS * 4);
    float* minv = (float*)alloc((size_t)N_SLOTS * 4);

    prep_z_k<<<B_ROWS / 4, 256, 0, stream>>>(z, zinv);
    prep_mem_k<<<N_SLOTS / 4, 256, 0, stream>>>(mem, minv);
    stats_k<<<B_ROWS / BM, 256, 0, stream>>>(z, mem, zinv, minv, rowmax, rowlinv, rowarg);
    zhat_k<<<B_ROWS / 64, 512, 0, stream>>>(z, mem, zinv, minv, rowmax, rowlinv, out_zhat);
    slot_update_k<<<N_SLOTS, 256, 0, stream>>>(mem, z, rowmax, rowarg, out_mem);
}

// Round 6
// 1656.130 us; speedup vs baseline: 2.6313x; 1.1632x over previous
//
#include <hip/hip_runtime.h>
#include <math.h>

#define B_ROWS 32768
#define N_SLOTS 2048
#define H_DIM 512
#define MCAP 4096

typedef __attribute__((ext_vector_type(8))) short bf16x8;
typedef __attribute__((ext_vector_type(4))) float f32x4;

#define ZST 72    // Zc/Ml stride (bf16): 16B-aligned rows
#define ZPL 136   // Pl/Vl stride (bf16): 16B-aligned rows
#define FIX_MARGIN 1e-3f
#define XROWS 16

__device__ __forceinline__ unsigned short f2bf(float f) {
    unsigned u = __float_as_uint(f);
    unsigned r = 0x7fffu + ((u >> 16) & 1u);
    return (unsigned short)((u + r) >> 16);
}
__device__ __forceinline__ unsigned pk2(float a, float b) {
    return (unsigned)f2bf(a) | ((unsigned)f2bf(b) << 16);
}

// ---------------- prep: reciprocal norms ----------------

__global__ __launch_bounds__(256) void prep_z_k(const float* __restrict__ z,
                                                float* __restrict__ zinv) {
    int row = blockIdx.x * 4 + (threadIdx.x >> 6);
    int lane = threadIdx.x & 63;
    const float4* p = reinterpret_cast<const float4*>(z + (size_t)row * H_DIM);
    float4 a = p[lane * 2];
    float4 b = p[lane * 2 + 1];
    float s = a.x * a.x + a.y * a.y + a.z * a.z + a.w * a.w
            + b.x * b.x + b.y * b.y + b.z * b.z + b.w * b.w;
#pragma unroll
    for (int m = 32; m >= 1; m >>= 1) s += __shfl_xor(s, m, 64);
    if (lane == 0) zinv[row] = 1.0f / fmaxf(sqrtf(s), 1e-12f);
}

__global__ __launch_bounds__(256) void prep_mem_k(const float* __restrict__ mem,
                                                  float* __restrict__ minv) {
    int row = blockIdx.x * 4 + (threadIdx.x >> 6);
    int lane = threadIdx.x & 63;
    const float4* p = reinterpret_cast<const float4*>(mem + (size_t)row * H_DIM);
    float4 a = p[lane * 2];
    float4 b = p[lane * 2 + 1];
    float s = a.x * a.x + a.y * a.y + a.z * a.z + a.w * a.w
            + b.x * b.x + b.y * b.y + b.z * b.z + b.w * b.w;
#pragma unroll
    for (int m = 32; m >= 1; m >>= 1) s += __shfl_xor(s, m, 64);
    if (lane == 0) minv[row] = 1.0f / fmaxf(sqrtf(s), 1e-12f);
}

// ---------------- fused zhat + online stats (flash-style, bf16 MFMA) ----------------

__global__ __launch_bounds__(512, 2) void zhat_k(const float* __restrict__ z,
                                                 const float* __restrict__ mem,
                                                 const float* __restrict__ zinv,
                                                 const float* __restrict__ minv,
                                                 float* __restrict__ rowmax,
                                                 int* __restrict__ rowarg,
                                                 float* __restrict__ rowm2,
                                                 int* __restrict__ rowa2,
                                                 float* __restrict__ out) {
    __shared__ __align__(16) short Pl[64 * ZPL];
    __shared__ __align__(16) short Stage[192 * ZST];    // Zc[64] + Ml[128]; Vl aliases
    __shared__ float Mi[N_SLOTS];
    __shared__ float Zi[64];
    __shared__ float M1[64], M2[64], Lr[64], Al[64];
    __shared__ int A1[64], A2[64];
    __shared__ float pm1[2][64], pm2[2][64], ps[2][64];
    __shared__ int pa1[2][64], pa2[2][64];

    short* Zc = Stage;
    short* Ml = Stage + 64 * ZST;
    short* Vl = Stage;

    int tid = threadIdx.x;
    int row0 = blockIdx.x * 64;
    int wave = tid >> 6, lane = tid & 63;
    int lm = lane & 15, quad = lane >> 4;
    int rt = wave & 3;
    int wg = wave >> 2;

    int zr = tid >> 3, zk0 = (tid & 7) * 8;
    int msl = tid >> 2, mk0 = (tid & 3) * 16;
    int vh = lane;

    for (int i = tid; i < N_SLOTS; i += 512) Mi[i] = minv[i];
    if (tid < 64) {
        Zi[tid] = zinv[row0 + tid];
        M1[tid] = -3.4e38f; M2[tid] = -3.4e38f;
        Lr[tid] = 0.f;
    }

    f32x4 acc[16];
#pragma unroll
    for (int t = 0; t < 16; ++t) acc[t] = (f32x4){0.f, 0.f, 0.f, 0.f};
    __syncthreads();

    for (int ct = 0; ct < 16; ++ct) {
        int col0 = ct * 128;

        f32x4 sacc[4];
#pragma unroll
        for (int i = 0; i < 4; ++i) sacc[i] = (f32x4){0.f, 0.f, 0.f, 0.f};

        for (int kc = 0; kc < H_DIM; kc += 64) {
            {
                const float* src = z + (size_t)(row0 + zr) * H_DIM + kc + zk0;
                float4 a = *reinterpret_cast<const float4*>(src);
                float4 b = *reinterpret_cast<const float4*>(src + 4);
                uint4 pz = {pk2(a.x, a.y), pk2(a.z, a.w), pk2(b.x, b.y), pk2(b.z, b.w)};
                *reinterpret_cast<uint4*>(&Zc[zr * ZST + zk0]) = pz;

                const float* ms = mem + (size_t)(col0 + msl) * H_DIM + kc + mk0;
#pragma unroll
                for (int j = 0; j < 4; ++j) {
                    float4 v = *reinterpret_cast<const float4*>(ms + j * 4);
                    uint2 pm = {pk2(v.x, v.y), pk2(v.z, v.w)};
                    *reinterpret_cast<uint2*>(&Ml[msl * ZST + mk0 + j * 4]) = pm;
                }
            }
            __syncthreads();
#pragma unroll
            for (int ks = 0; ks < 2; ++ks) {
                bf16x8 af = *reinterpret_cast<const bf16x8*>(&Zc[(rt * 16 + lm) * ZST + ks * 32 + quad * 8]);
#pragma unroll
                for (int i = 0; i < 4; ++i) {
                    bf16x8 bfr = *reinterpret_cast<const bf16x8*>(&Ml[((wg * 4 + i) * 16 + lm) * ZST + ks * 32 + quad * 8]);
                    sacc[i] = __builtin_amdgcn_mfma_f32_16x16x32_bf16(af, bfr, sacc[i], 0, 0, 0);
                }
            }
            __syncthreads();
        }

        // ---- scale + per-thread/cross-lane top-2 ----
        float zir[4];
#pragma unroll
        for (int r = 0; r < 4; ++r) zir[r] = Zi[rt * 16 + quad * 4 + r];
        float m1v[4], m2v[4];
        int a1v[4], a2v[4];
#pragma unroll
        for (int r = 0; r < 4; ++r) { m1v[r] = -3.4e38f; m2v[r] = -3.4e38f; a1v[r] = 0; a2v[r] = 0; }
#pragma unroll
        for (int i = 0; i < 4; ++i) {
            int slot_l = (wg * 4 + i) * 16 + lm;
            float mvv = Mi[col0 + slot_l];
            int sg = col0 + slot_l;
#pragma unroll
            for (int r = 0; r < 4; ++r) {
                float v = sacc[i][r] * zir[r] * mvv;
                sacc[i][r] = v;
                if (v > m1v[r]) { m2v[r] = m1v[r]; a2v[r] = a1v[r]; m1v[r] = v; a1v[r] = sg; }
                else if (v > m2v[r]) { m2v[r] = v; a2v[r] = sg; }
            }
        }
#pragma unroll
        for (int mk = 1; mk < 16; mk <<= 1) {
#pragma unroll
            for (int r = 0; r < 4; ++r) {
                float n1 = __shfl_xor(m1v[r], mk, 16);
                int b1 = __shfl_xor(a1v[r], mk, 16);
                float n2 = __shfl_xor(m2v[r], mk, 16);
                int b2 = __shfl_xor(a2v[r], mk, 16);
                if (n1 > m1v[r]) {
                    bool c = m1v[r] > n2;
                    m2v[r] = c ? m1v[r] : n2; a2v[r] = c ? a1v[r] : b2;
                    m1v[r] = n1; a1v[r] = b1;
                } else {
                    bool c = n1 > m2v[r];
                    m2v[r] = c ? n1 : m2v[r]; a2v[r] = c ? b1 : a2v[r];
                }
            }
        }
        if (lm == 0) {
#pragma unroll
            for (int r = 0; r < 4; ++r) {
                int rl = rt * 16 + quad * 4 + r;
                pm1[wg][rl] = m1v[r]; pa1[wg][rl] = a1v[r];
                pm2[wg][rl] = m2v[r]; pa2[wg][rl] = a2v[r];
            }
        }
        __syncthreads();

        if (wave == 0) {
            int r = lane;
            float gm1 = M1[r], gm2 = M2[r];
            int ga1 = A1[r], ga2 = A2[r];
            float old = gm1;
#pragma unroll
            for (int w2 = 0; w2 < 2; ++w2) {
                float n1 = pm1[w2][r]; int b1 = pa1[w2][r];
                float n2 = pm2[w2][r]; int b2 = pa2[w2][r];
                if (n1 > gm1) {
                    bool c = gm1 > n2;
                    gm2 = c ? gm1 : n2; ga2 = c ? ga1 : b2;
                    gm1 = n1; ga1 = b1;
                } else {
                    bool c = n1 > gm2;
                    gm2 = c ? n1 : gm2; ga2 = c ? b1 : ga2;
                }
            }
            float alpha = __expf(old - gm1);
            M1[r] = gm1; A1[r] = ga1; M2[r] = gm2; A2[r] = ga2;
            Al[r] = alpha; Lr[r] *= alpha;
        }
        __syncthreads();

        float alr[4], m1r[4];
#pragma unroll
        for (int r = 0; r < 4; ++r) {
            int rl = rt * 16 + quad * 4 + r;
            alr[r] = Al[rl]; m1r[r] = M1[rl];
        }
#pragma unroll
        for (int t = 0; t < 16; ++t)
#pragma unroll
            for (int r = 0; r < 4; ++r) acc[t][r] *= alr[r];
        float ps4[4] = {0.f, 0.f, 0.f, 0.f};
#pragma unroll
        for (int i = 0; i < 4; ++i) {
            int slot_l = (wg * 4 + i) * 16 + lm;
#pragma unroll
            for (int r = 0; r < 4; ++r) {
                float p = __expf(sacc[i][r] - m1r[r]);
                ps4[r] += p;
                Pl[(rt * 16 + quad * 4 + r) * ZPL + slot_l] = (short)f2bf(p);
            }
        }
#pragma unroll
        for (int mk = 1; mk < 16; mk <<= 1)
#pragma unroll
            for (int r = 0; r < 4; ++r) ps4[r] += __shfl_xor(ps4[r], mk, 16);
        if (lm == 0)
#pragma unroll
            for (int r = 0; r < 4; ++r) ps[wg][rt * 16 + quad * 4 + r] = ps4[r];
        __syncthreads();

        for (int hc = 0; hc < 8; ++hc) {
            if (hc == 0 && wave == 0) Lr[lane] += ps[0][lane] + ps[1][lane];
#pragma unroll
            for (int it = 0; it < 4; ++it) {
                int s0 = wave * 4 + it * 32;
                const float* vs = mem + (size_t)(col0 + s0) * H_DIM + hc * 64 + vh;
                float f0 = vs[0], f1 = vs[H_DIM], f2 = vs[2 * H_DIM], f3 = vs[3 * H_DIM];
                uint2 pv = {pk2(f0, f1), pk2(f2, f3)};
                *reinterpret_cast<uint2*>(&Vl[vh * ZPL + s0]) = pv;
            }
            __syncthreads();
#pragma unroll
            for (int ks = 0; ks < 4; ++ks) {
                bf16x8 af = *reinterpret_cast<const bf16x8*>(&Pl[(rt * 16 + lm) * ZPL + ks * 32 + quad * 8]);
#pragma unroll
                for (int i = 0; i < 2; ++i) {
                    int hl = (wg * 2 + i) * 16 + lm;
                    bf16x8 bfr = *reinterpret_cast<const bf16x8*>(&Vl[hl * ZPL + ks * 32 + quad * 8]);
                    int t = hc * 2 + i;
                    acc[t] = __builtin_amdgcn_mfma_f32_16x16x32_bf16(af, bfr, acc[t], 0, 0, 0);
                }
            }
            __syncthreads();
        }
    }

    float linv[4];
#pragma unroll
    for (int r = 0; r < 4; ++r) linv[r] = 1.0f / Lr[rt * 16 + quad * 4 + r];
#pragma unroll
    for (int hc = 0; hc < 8; ++hc)
#pragma unroll
        for (int i = 0; i < 2; ++i) {
            int t = hc * 2 + i;
            int h = hc * 64 + (wg * 2 + i) * 16 + lm;
#pragma unroll
            for (int r = 0; r < 4; ++r) {
                int rg = row0 + rt * 16 + quad * 4 + r;
                out[(size_t)rg * H_DIM + h] = acc[t][r] * linv[r];
            }
        }
    if (wave == 0) {
        rowmax[row0 + lane] = M1[lane];
        rowarg[row0 + lane] = A1[lane];
        rowm2[row0 + lane] = M2[lane];
        rowa2[row0 + lane] = A2[lane];
    }
}

// ---------------- flag near-tie rows into a compact worklist ----------------

__global__ void zero_k(int* __restrict__ cnt) {
    if (threadIdx.x == 0) *cnt = 0;
}

__global__ __launch_bounds__(256) void flag_k(const float* __restrict__ rowmax,
                                              const float* __restrict__ rowm2,
                                              int* __restrict__ cnt,
                                              int* __restrict__ list) {
    int b = blockIdx.x * 256 + threadIdx.x;
    if (rowmax[b] - rowm2[b] < FIX_MARGIN) {
        int p = atomicAdd(cnt, 1);
        list[p] = b;
    }
}

// ---------------- exact: full fp32 argmax over all slots for flagged rows ----------------
// grid-stride over groups of 16 gathered rows; mini fp32 GEMM 16x2048xK512.

__global__ __launch_bounds__(256) void exact_k(const float* __restrict__ z,
                                               const float* __restrict__ mem,
                                               const float* __restrict__ minv,
                                               const int* __restrict__ cnt,
                                               const int* __restrict__ list,
                                               int* __restrict__ rowarg) {
    __shared__ float As[32][XROWS + 4];
    __shared__ float Bs[32][132];
    __shared__ int rows[XROWS];
    int tid = threadIdx.x;
    int tx = tid & 15, ty = tid >> 4;   // ty = row (0..15), tx = slot octet
    int n = *cnt;
    int ngroups = (n + XROWS - 1) / XROWS;

    for (int g = blockIdx.x; g < ngroups; g += gridDim.x) {
        if (tid < XROWS) {
            int idx = g * XROWS + tid;
            rows[tid] = list[idx < n ? idx : n - 1];
        }
        __syncthreads();
        float runM = -3.4e38f;
        int runA = 0;
        for (int ct = 0; ct < 16; ++ct) {
            int col0 = ct * 128;
            float acc[8];
#pragma unroll
            for (int j = 0; j < 8; ++j) acc[j] = 0.f;
            for (int kc = 0; kc < H_DIM; kc += 32) {
                if (tid < 128) {
                    int r = tid >> 3, k4 = (tid & 7) * 4;
                    float4 v = *reinterpret_cast<const float4*>(z + (size_t)rows[r] * H_DIM + kc + k4);
                    As[k4 + 0][r] = v.x;
                    As[k4 + 1][r] = v.y;
                    As[k4 + 2][r] = v.z;
                    As[k4 + 3][r] = v.w;
                }
                int sl = tid >> 1, kq = (tid & 1) * 16;
#pragma unroll
                for (int j = 0; j < 4; ++j) {
                    float4 v = *reinterpret_cast<const float4*>(mem + (size_t)(col0 + sl) * H_DIM + kc + kq + j * 4);
                    Bs[kq + j * 4 + 0][sl] = v.x;
                    Bs[kq + j * 4 + 1][sl] = v.y;
                    Bs[kq + j * 4 + 2][sl] = v.z;
                    Bs[kq + j * 4 + 3][sl] = v.w;
                }
                __syncthreads();
#pragma unroll 4
                for (int k = 0; k < 32; ++k) {
                    float av = As[k][ty];
                    const float4 b0 = *reinterpret_cast<const float4*>(&Bs[k][tx * 8]);
                    const float4 b1 = *reinterpret_cast<const float4*>(&Bs[k][tx * 8 + 4]);
                    acc[0] = fmaf(av, b0.x, acc[0]);
                    acc[1] = fmaf(av, b0.y, acc[1]);
                    acc[2] = fmaf(av, b0.z, acc[2]);
                    acc[3] = fmaf(av, b0.w, acc[3]);
                    acc[4] = fmaf(av, b1.x, acc[4]);
                    acc[5] = fmaf(av, b1.y, acc[5]);
                    acc[6] = fmaf(av, b1.z, acc[6]);
                    acc[7] = fmaf(av, b1.w, acc[7]);
                }
                __syncthreads();
            }
#pragma unroll
            for (int j = 0; j < 8; ++j) {
                int sg = col0 + tx * 8 + j;
                float s = acc[j] * minv[sg];   // zinv is a common positive factor: argmax-invariant
                if (s > runM) { runM = s; runA = sg; }
            }
        }
#pragma unroll
        for (int mk = 1; mk < 16; mk <<= 1) {
            float om = __shfl_xor(runM, mk, 16);
            int oa = __shfl_xor(runA, mk, 16);
            if (om > runM || (om == runM && oa < runA)) { runM = om; runA = oa; }
        }
        if (tx == 0) {
            int idx = g * XROWS + ty;
            if (idx < n) rowarg[rows[ty]] = runA;
        }
        __syncthreads();
    }
}

// ---------------- refine: fp32 rowmax for ALL rows given final argmax ----------------

__global__ __launch_bounds__(256) void refine_k(const float* __restrict__ z,
                                                const float* __restrict__ mem,
                                                const float* __restrict__ zinv,
                                                const float* __restrict__ minv,
                                                const int* __restrict__ rowarg,
                                                float* __restrict__ rowmax) {
    int row = blockIdx.x * 4 + (threadIdx.x >> 6);
    int lane = threadIdx.x & 63;
    int a = rowarg[row];
    const float4* zp = reinterpret_cast<const float4*>(z + (size_t)row * H_DIM);
    const float4* mp = reinterpret_cast<const float4*>(mem + (size_t)a * H_DIM);
    float d = 0.f;
#pragma unroll
    for (int j = 0; j < 2; ++j) {
        float4 x = zp[lane + j * 64];
        float4 y = mp[lane + j * 64];
        d += x.x * y.x + x.y * y.y + x.z * y.z + x.w * y.w;
    }
#pragma unroll
    for (int m = 32; m >= 1; m >>= 1) d += __shfl_xor(d, m, 64);
    if (lane == 0) rowmax[row] = d * zinv[row] * minv[a];
}

// ---------------- per-slot update: gather members, masked softmax, renormalize ----------------

__global__ __launch_bounds__(256) void slot_update_k(const float* __restrict__ mem,
                                                     const float* __restrict__ z,
                                                     const float* __restrict__ rowmax,
                                                     const int* __restrict__ rowarg,
                                                     float* __restrict__ outmem) {
    __shared__ int members[MCAP];
    __shared__ float uval[MCAP];
    __shared__ int cnt;
    __shared__ float red[4];
    __shared__ float bcast;
    int slot = blockIdx.x, tid = threadIdx.x;
    if (tid == 0) cnt = 0;
    __syncthreads();
    for (int b = tid; b < B_ROWS; b += 256) {
        if (rowarg[b] == slot) {
            int p = atomicAdd(&cnt, 1);
            if (p < MCAP) members[p] = b;
        }
    }
    __syncthreads();
    int n = min(cnt, MCAP);
    size_t base = (size_t)slot * H_DIM;
    if (n == 0) {
        for (int h = tid; h < H_DIM; h += 256) outmem[base + h] = mem[base + h];
        return;
    }
    float lm = -3.4e38f;
    for (int j = tid; j < n; j += 256) lm = fmaxf(lm, rowmax[members[j]]);
#pragma unroll
    for (int m = 32; m >= 1; m >>= 1) lm = fmaxf(lm, __shfl_xor(lm, m, 64));
    if ((tid & 63) == 0) red[tid >> 6] = lm;
    __syncthreads();
    if (tid == 0) bcast = fmaxf(fmaxf(red[0], red[1]), fmaxf(red[2], red[3]));
    __syncthreads();
    float mslot = bcast;
    __syncthreads();
    float ls = 0.f;
    for (int j = tid; j < n; j += 256) {
        float u = expf(rowmax[members[j]] - mslot);
        uval[j] = u;
        ls += u;
    }
#pragma unroll
    for (int m = 32; m >= 1; m >>= 1) ls += __shfl_xor(ls, m, 64);
    if ((tid & 63) == 0) red[tid >> 6] = ls;
    __syncthreads();
    if (tid == 0) bcast = (red[0] + red[1]) + (red[2] + red[3]);
    __syncthreads();
    float dinv = 1.0f / fmaxf(bcast, 1e-30f);
    float v0 = mem[base + tid];
    float v1 = mem[base + 256 + tid];
    for (int j = 0; j < n; ++j) {
        float u = uval[j] * dinv;
        size_t zb = (size_t)members[j] * H_DIM;
        v0 = fmaf(u, z[zb + tid], v0);
        v1 = fmaf(u, z[zb + 256 + tid], v1);
    }
    float s = v0 * v0 + v1 * v1;
#pragma unroll
    for (int m = 32; m >= 1; m >>= 1) s += __shfl_xor(s, m, 64);
    if ((tid & 63) == 0) red[tid >> 6] = s;
    __syncthreads();
    if (tid == 0) bcast = (red[0] + red[1]) + (red[2] + red[3]);
    __syncthreads();
    float ninv = 1.0f / fmaxf(sqrtf(bcast), 1e-12f);
    outmem[base + tid] = v0 * ninv;
    outmem[base + 256 + tid] = v1 * ninv;
}

// ---------------- launch ----------------

extern "C" void kernel_launch(void* const* d_in, const int* in_sizes, int n_in,
                              void* d_out, int out_size, void* d_ws, size_t ws_size,
                              hipStream_t stream) {
    const float* z = (const float*)d_in[0];
    const float* mem = (const float*)d_in[1];
    float* out_zhat = (float*)d_out;
    float* out_mem = out_zhat + (size_t)B_ROWS * H_DIM;

    char* ws = (char*)d_ws;
    size_t off = 0;
    auto alloc = [&](size_t bytes) -> void* {
        void* p = ws + off;
        off += (bytes + 255) & ~(size_t)255;
        return p;
    };
    float* rowmax = (float*)alloc((size_t)B_ROWS * 4);
    int* rowarg = (int*)alloc((size_t)B_ROWS * 4);
    float* rowm2 = (float*)alloc((size_t)B_ROWS * 4);
    int* rowa2 = (int*)alloc((size_t)B_ROWS * 4);
    float* zinv = (float*)alloc((size_t)B_ROWS * 4);
    float* minv = (float*)alloc((size_t)N_SLOTS * 4);
    int* fcnt = (int*)alloc(256);
    int* flist = (int*)alloc((size_t)B_ROWS * 4);

    prep_z_k<<<B_ROWS / 4, 256, 0, stream>>>(z, zinv);
    prep_mem_k<<<N_SLOTS / 4, 256, 0, stream>>>(mem, minv);
    zhat_k<<<B_ROWS / 64, 512, 0, stream>>>(z, mem, zinv, minv,
                                            rowmax, rowarg, rowm2, rowa2, out_zhat);
    zero_k<<<1, 64, 0, stream>>>(fcnt);
    flag_k<<<B_ROWS / 256, 256, 0, stream>>>(rowmax, rowm2, fcnt, flist);
    exact_k<<<256, 256, 0, stream>>>(z, mem, minv, fcnt, flist, rowarg);
    refine_k<<<B_ROWS / 4, 256, 0, stream>>>(z, mem, zinv, minv, rowarg, rowmax);
    slot_update_k<<<N_SLOTS, 256, 0, stream>>>(mem, z, rowmax, rowarg, out_mem);
}